// Round 7
// baseline (225.125 us; speedup 1.0000x reference)
//
#include <hip/hip_runtime.h>
#include <hip/hip_bf16.h>
#include <stdint.h>

typedef __bf16 bf16_t;
typedef bf16_t bf16x8 __attribute__((ext_vector_type(8)));
typedef float f32x4 __attribute__((ext_vector_type(4)));

#define BM 256
#define BN 256
#define BK 64

// ---------------------------------------------------------------------------
// async global->LDS 16B copy. LDS dest is wave-uniform base; HW adds lane*16.
// ---------------------------------------------------------------------------
__device__ __forceinline__ void gload_lds16(const void* g, void* l) {
  __builtin_amdgcn_global_load_lds(
      (const __attribute__((address_space(1))) uint32_t*)g,
      (__attribute__((address_space(3))) uint32_t*)l, 16, 0, 0);
}

// ---------------------------------------------------------------------------
// fused fp32->bf16 conversion: blocks [0,gx) convert x, [gx,..) convert
// weight (per-out-channel scale folded in). 8 elems/thread, grid-stride.
// ---------------------------------------------------------------------------
__global__ __launch_bounds__(256) void cvt_kernel(
    const float* __restrict__ x, bf16_t* __restrict__ xo, int n8x,
    const float* __restrict__ w, const float* __restrict__ scale,
    bf16_t* __restrict__ wo, int k8, int n8w, int gx) {
  if ((int)blockIdx.x < gx) {
    int stride = gx * blockDim.x;
    for (int i = blockIdx.x * blockDim.x + threadIdx.x; i < n8x; i += stride) {
      const f32x4* p = (const f32x4*)x + 2 * (size_t)i;
      f32x4 a = p[0], b = p[1];
      bf16x8 o;
#pragma unroll
      for (int r = 0; r < 4; ++r) { o[r] = (bf16_t)a[r]; o[r + 4] = (bf16_t)b[r]; }
      *((bf16x8*)xo + i) = o;
    }
  } else {
    int stride = (gridDim.x - gx) * blockDim.x;
    for (int i = (blockIdx.x - gx) * blockDim.x + threadIdx.x; i < n8w;
         i += stride) {
      int row = i / k8;
      float s = scale[row];
      const f32x4* p = (const f32x4*)w + 2 * (size_t)i;
      f32x4 a = p[0], b = p[1];
      bf16x8 o;
#pragma unroll
      for (int r = 0; r < 4; ++r) {
        o[r] = (bf16_t)(a[r] * s);
        o[r + 4] = (bf16_t)(b[r] * s);
      }
      *((bf16x8*)wo + i) = o;
    }
  }
}

// ---------------------------------------------------------------------------
// 256x256 bf16 GEMM, both K-major (B^T), 16x16x32 MFMA (r4 schedule).
// 8 waves (2Mx4N), per-wave out 128x64. 4 phases/K-tile, ONE barrier/phase,
// cross-phase register prefetch; counted vmcnt(6)@P3 / vmcnt(4)@P4.
// r7 deltas vs r4 (sync structure IDENTICAL, hazard ledger unchanged):
//   - 2-K-tile unroll: buffer bases are compile-time -> ds_read = base VGPR
//     (loop-invariant) + 16-bit immediate, no per-iteration address VALU.
//   - stage issues hoisted to phase top (issue-early; vmcnt/lgkm order kept).
//
// Hazard ledger (steady state, tile t; BB=t&1 buf, NB=other):
//   stage: P1: A-K1(t+1)->NB  P2: B-K1(t+1)->NB  P3: A-K0(t+2)->BB
//          P4: B-K0(t+2)->BB
//   reads: P1: aY=A(ch1,K0,BB)   P2: aX=A(ch0,K1,BB)+b1=B-K1(BB)
//          P3: aY=A(ch1,K1,BB)   P4: aX=A(ch0,K0,NB)+b0=B-K0(NB)
//   vmcnt(6)@P3(t): queue=[K0(t+1)x4, K1(t+1)x4, A-K0(t+2)x2] -> drains
//     K0(t+1) (read by P4(t)); vmcnt(4)@P4(t): drains K1(t+1) (read P2(t+1)).
//   lgkm counts: each phase's wait leaves only the just-issued prefetch
//     outstanding and drains this phase's MFMA operands (FIFO-verified).
//   WAR: every region re-stage is >=1 barrier after its last reader's lgkm.
//
// LDS swizzle: chunk-XOR s(row)=(row>>1)&3 at 16B granularity — measured
// 0 SQ_LDS_BANK_CONFLICT (r3-r5); staging pre-applies it on the global src.
// ---------------------------------------------------------------------------
__global__ __launch_bounds__(512, 2) void gemm256(
    const bf16_t* __restrict__ A, const bf16_t* __restrict__ B,
    const float* __restrict__ bias, float* __restrict__ C,
    int M, int N, int K) {
  __shared__ __attribute__((aligned(16))) char lds[131072];

  const int tid = threadIdx.x;
  const int lane = tid & 63;
  const int wave = tid >> 6;
  const int wm = wave >> 2;   // 0..1  (row half of tile)
  const int wn = wave & 3;    // 0..3  (col quarter of tile)

  // XCD-aware bijective swizzle
  int nwg = gridDim.x;
  int wg = blockIdx.x;
  if ((nwg & 7) == 0) { int cpx = nwg >> 3; wg = (wg & 7) * cpx + (wg >> 3); }
  const int ntn = N / BN;
  const int tm = wg / ntn;
  const int tn = wg % ntn;

  const size_t Kb = (size_t)K * 2;
  const char* gApan = (const char*)A + (size_t)tm * BM * Kb;
  const char* gBpan = (const char*)B + (size_t)tn * BN * Kb;

  // ---- per-lane read bases; buffer variants precomputed (loop-invariant) ---
  const int xc = (((lane >> 4) ^ ((lane >> 1) & 3)) << 4);
  const int aBase = (wm * 128 + (lane & 15)) * 64 + xc;  // + ch*4096 + i*1024
  const int bBase = (wn * 64 + (lane & 15)) * 64 + xc;   // + j*1024
  const char* pA0 = lds + aBase;           // buf0 A base
  const char* pA1 = lds + 65536 + aBase;   // buf1 A base
  const char* pB0 = lds + bBase;           // buf0 B base (+32768/+49152 imm)
  const char* pB1 = lds + 65536 + bBase;   // buf1 B base

  // ---- staging offsets: wave w covers rows [(2w+s)*16, +16) of a unit ----
  size_t srcoff[2];
  int ldst[2];
#pragma unroll
  for (int s = 0; s < 2; ++s) {
    int r = (wave * 2 + s) * 16 + (lane >> 2);
    int c = (lane & 3) ^ ((lane >> 3) & 3);
    srcoff[s] = (size_t)r * Kb + (size_t)(c << 4);
    ldst[s] = (wave * 2 + s) * 1024;
  }

#define STAGE_U(dstc, pan, kbyte)                                             \
  {                                                                           \
    gload_lds16((pan) + srcoff[0] + (size_t)(kbyte), lds + (dstc) + ldst[0]); \
    gload_lds16((pan) + srcoff[1] + (size_t)(kbyte), lds + (dstc) + ldst[1]); \
  }
#define RD_A(dst, P, u, ch)                                                   \
  _Pragma("unroll") for (int i_ = 0; i_ < 4; ++i_)                            \
      dst[i_] = *(const bf16x8*)((P) + (u) + (ch) * 4096 + i_ * 1024);
#define RD_B(dst, P, u)                                                       \
  _Pragma("unroll") for (int j_ = 0; j_ < 4; ++j_)                            \
      dst[j_] = *(const bf16x8*)((P) + (u) + j_ * 1024);
#define MFMA16(ab, bb_, accbase)                                              \
  __builtin_amdgcn_s_setprio(1);                                              \
  _Pragma("unroll") for (int i_ = 0; i_ < 4; ++i_)                            \
      _Pragma("unroll") for (int j_ = 0; j_ < 4; ++j_)                        \
          acc[(accbase) + i_][j_] = __builtin_amdgcn_mfma_f32_16x16x32_bf16(  \
              ab[i_], bb_[j_], acc[(accbase) + i_][j_], 0, 0, 0);             \
  __builtin_amdgcn_s_setprio(0);
#define WAIT_LGKM(n) asm volatile("s_waitcnt lgkmcnt(" #n ")" ::: "memory")
#define WAIT_VM(n)   asm volatile("s_waitcnt vmcnt(" #n ")" ::: "memory")
#define BAR()        __builtin_amdgcn_s_barrier()

  // One K-tile, sync structure identical to r4. aBB/bBB: this tile's bases;
  // aNB/bNB: next tile's; BBc/NBc: compile-time LDS region constants.
#define TILE(t_, aBB, bBB, aNB, bNB, BBc, NBc)                                \
  {                                                                           \
    const bool st1 = (t_) + 1 < NT;                                           \
    const bool st2 = (t_) + 2 < NT;                                           \
    const size_t kb1 = (size_t)((t_) + 1) * 128;                              \
    const size_t kb2 = (size_t)((t_) + 2) * 128;                              \
    /* P1: MFMA(aX, b0); prefetch aY = A(ch1,K0) */                           \
    if (st1) STAGE_U((NBc) + 16384, gApan, kb1 + 64);                         \
    RD_A(aY, aBB, 0, 1);                                                      \
    WAIT_LGKM(4);                                                             \
    MFMA16(aX, b0, 0);                                                        \
    BAR();                                                                    \
    /* P2: MFMA(aY, b0); prefetch aX = A(ch0,K1), b1 = B-K1 */                \
    if (st1) STAGE_U((NBc) + 49152, gBpan, kb1 + 64);                         \
    RD_A(aX, aBB, 16384, 0);                                                  \
    RD_B(b1, bBB, 49152);                                                     \
    WAIT_LGKM(8);                                                             \
    MFMA16(aY, b0, 4);                                                        \
    BAR();                                                                    \
    /* P3: MFMA(aX, b1); prefetch aY = A(ch1,K1) */                           \
    if (st2) STAGE_U((BBc), gApan, kb2);                                      \
    RD_A(aY, aBB, 16384, 1);                                                  \
    WAIT_LGKM(4);                                                             \
    MFMA16(aX, b1, 0);                                                        \
    if (st2) { WAIT_VM(6); } else if (st1) { WAIT_VM(4); } else { WAIT_VM(0); } \
    BAR();                                                                    \
    /* P4: MFMA(aY, b1); prefetch next tile's aX, b0 */                       \
    if (st2) STAGE_U((BBc) + 32768, gBpan, kb2);                              \
    if (st1) { RD_A(aX, aNB, 0, 0); RD_B(b0, bNB, 32768); }                   \
    if (st1) { WAIT_LGKM(8); } else { WAIT_LGKM(0); }                         \
    MFMA16(aY, b1, 4);                                                        \
    if (st2) { WAIT_VM(4); } else { WAIT_VM(0); }                             \
    BAR();                                                                    \
  }

  f32x4 acc[8][4];
#pragma unroll
  for (int a = 0; a < 8; ++a)
#pragma unroll
    for (int j = 0; j < 4; ++j) acc[a][j] = (f32x4)0.0f;

  const int NT = K / BK;

  // ---- prologue: tile0 (4 units) + tile1 K0 (2 units); 2 left in flight ----
  STAGE_U(0,             gApan, 0);
  STAGE_U(32768,         gBpan, 0);
  STAGE_U(16384,         gApan, 64);
  STAGE_U(49152,         gBpan, 64);
  if (NT > 1) {
    STAGE_U(65536,         gApan, 128);
    STAGE_U(65536 + 32768, gBpan, 128);
    WAIT_VM(4);
  } else {
    WAIT_VM(0);
  }
  BAR();

  bf16x8 aX[4], aY[4], b0[4], b1[4];
  RD_A(aX, pA0, 0, 0);        // A(ch0,K0) tile0; drained by P1(0)'s lgkm(4)
  RD_B(b0, pB0, 32768);       // B-K0 tile0

  for (int t = 0; t < NT; t += 2) {
    TILE(t,     pA0, pB0, pA1, pB1, 0,     65536);
    TILE(t + 1, pA1, pB1, pA0, pB0, 65536, 0);
  }
#undef STAGE_U
#undef RD_A
#undef RD_B
#undef MFMA16
#undef WAIT_LGKM
#undef WAIT_VM
#undef BAR
#undef TILE

  // ---- epilogue: bias + store. C/D: col=lane&15, row=(lane>>4)*4+r ----
  const int row0 = tm * BM + wm * 128;
  const int col0 = tn * BN + wn * 64;
#pragma unroll
  for (int j = 0; j < 4; ++j) {
    int c = col0 + j * 16 + (lane & 15);
    float bv = bias[c];
#pragma unroll
    for (int a = 0; a < 8; ++a) {
      int ch = a >> 2, i = a & 3;
      int rbase = row0 + ch * 64 + i * 16 + ((lane >> 4) << 2);
#pragma unroll
      for (int r = 0; r < 4; ++r)
        C[(size_t)(rbase + r) * N + c] = acc[a][j][r] + bv;
    }
  }
}

// ---------------------------------------------------------------------------
// fallback: naive fp32 (only if workspace/shape unsuitable — correctness net)
// ---------------------------------------------------------------------------
__global__ void fallback_gemm(const float* __restrict__ x,
                              const float* __restrict__ w,
                              const float* __restrict__ s,
                              const float* __restrict__ b,
                              float* __restrict__ out, int M, int N, int K) {
  int o = blockIdx.x * blockDim.x + threadIdx.x;
  if (o >= M * N) return;
  int m = o / N, n = o % N;
  const float* xr = x + (size_t)m * K;
  const float* wr = w + (size_t)n * K;
  float acc = 0.f;
  for (int k = 0; k < K; ++k) acc += xr[k] * wr[k];
  out[o] = acc * s[n] + b[n];
}

extern "C" void kernel_launch(void* const* d_in, const int* in_sizes, int n_in,
                              void* d_out, int out_size, void* d_ws,
                              size_t ws_size, hipStream_t stream) {
  const float* x = (const float*)d_in[0];
  const float* w = (const float*)d_in[1];
  const float* sc = (const float*)d_in[2];
  const float* bias = (const float*)d_in[3];
  float* out = (float*)d_out;

  const int N = in_sizes[2];        // out_features (weight_scale length)
  const int K = in_sizes[1] / N;    // in_features
  const int M = in_sizes[0] / K;    // tokens

  const size_t need = ((size_t)M * K + (size_t)N * K) * sizeof(bf16_t);
  const int NT = K / BK;
  const bool fast = (ws_size >= need) && (M % BM == 0) && (N % BN == 0) &&
                    (K % BK == 0) && (NT >= 2) && (NT % 2 == 0);

  if (fast) {
    bf16_t* xb = (bf16_t*)d_ws;
    bf16_t* wb = xb + (size_t)M * K;

    int n8x = (M * K) / 8;
    int n8w = (N * K) / 8;
    const int gx = 2048;
    cvt_kernel<<<gx + 2048, 256, 0, stream>>>(x, xb, n8x, w, sc, wb, K / 8,
                                              n8w, gx);

    dim3 grid((M / BM) * (N / BN));
    gemm256<<<grid, 512, 0, stream>>>(xb, wb, bias, out, M, N, K);
  } else {
    int total = M * N;
    fallback_gemm<<<(total + 255) / 256, 256, 0, stream>>>(x, w, sc, bias, out,
                                                           M, N, K);
  }
}

// Round 8
// 152.809 us; speedup vs baseline: 1.4732x; 1.4732x over previous
//
#include <hip/hip_runtime.h>
#include <hip/hip_bf16.h>
#include <stdint.h>

typedef __bf16 bf16_t;
typedef bf16_t bf16x8 __attribute__((ext_vector_type(8)));
typedef float f32x4 __attribute__((ext_vector_type(4)));

#define BM 256
#define BN 256
#define BK 64

// ---------------------------------------------------------------------------
// async global->LDS 16B copy. LDS dest is wave-uniform base; HW adds lane*16.
// ---------------------------------------------------------------------------
__device__ __forceinline__ void gload_lds16(const void* g, void* l) {
  __builtin_amdgcn_global_load_lds(
      (const __attribute__((address_space(1))) uint32_t*)g,
      (__attribute__((address_space(3))) uint32_t*)l, 16, 0, 0);
}

// ---------------------------------------------------------------------------
// fused fp32->bf16 conversion: blocks [0,gx) convert x, [gx,..) convert
// weight (per-out-channel scale folded in). 8 elems/thread, grid-stride.
// ---------------------------------------------------------------------------
__global__ __launch_bounds__(256) void cvt_kernel(
    const float* __restrict__ x, bf16_t* __restrict__ xo, int n8x,
    const float* __restrict__ w, const float* __restrict__ scale,
    bf16_t* __restrict__ wo, int k8, int n8w, int gx) {
  if ((int)blockIdx.x < gx) {
    int stride = gx * blockDim.x;
    for (int i = blockIdx.x * blockDim.x + threadIdx.x; i < n8x; i += stride) {
      const f32x4* p = (const f32x4*)x + 2 * (size_t)i;
      f32x4 a = p[0], b = p[1];
      bf16x8 o;
#pragma unroll
      for (int r = 0; r < 4; ++r) { o[r] = (bf16_t)a[r]; o[r + 4] = (bf16_t)b[r]; }
      *((bf16x8*)xo + i) = o;
    }
  } else {
    int stride = (gridDim.x - gx) * blockDim.x;
    for (int i = (blockIdx.x - gx) * blockDim.x + threadIdx.x; i < n8w;
         i += stride) {
      int row = i / k8;
      float s = scale[row];
      const f32x4* p = (const f32x4*)w + 2 * (size_t)i;
      f32x4 a = p[0], b = p[1];
      bf16x8 o;
#pragma unroll
      for (int r = 0; r < 4; ++r) {
        o[r] = (bf16_t)(a[r] * s);
        o[r + 4] = (bf16_t)(b[r] * s);
      }
      *((bf16x8*)wo + i) = o;
    }
  }
}

// ---------------------------------------------------------------------------
// 256x256 bf16 GEMM, m201-faithful geometry & schedule.
// Units: ROW-HALVES, 16KB = 128 rows x 64 K-cols (128B rows, 8 x 16B chunks).
//   buf bb=t&1 (64KB): A_lo @+0, A_hi @+16K, B_lo @+32K, B_hi @+48K.
// Swizzle: chunk XOR (row&7) at 16B granularity (G4's canonical fix):
//   LDS[row][c] = G[row][c ^ (row&7)]; staging pre-applies on global source
//   (linear LDS dest, HW requirement). Reader chunk = (hi+4*ks) ^ (row&7);
//   per 8-lane group covers all 32 banks, 2-way aliasing only (free, m136).
// Phases = C-quadrants x full K=64 with operand reuse (8 waves 2Mx4N, wave
// out 128x64; quadrant = 64x32 = 4x2 frags):
//   ph1: rd A(r0) 8 + B(c0) 4 [12 -> lgkm(8) throttle]; stage A_hi(t+1)->nb
//   ph2: rd B(c1) 4;                                     stage B_hi(t+1)->nb
//   ph3: rd A(r1) 8;                                     (no stage)
//   ph4: no reads (reuse b0);        stage A_lo(t+2)->bb, B_lo(t+2)->bb
// Each phase: {reads|stage|BAR|lgkm(0)|setprio1 16 MFMA setprio0|BAR};
// single vmcnt(4) per K-tile at ph4 (never 0 mid-loop).
// Ledger: vmcnt(4)@ph4(t) has 12 outstanding [A_lo/B_lo(t+1)@ph4(t-1)=4,
//   A_hi(t+1)@ph1(t)=2, B_hi(t+1)@ph2(t)=2, A_lo/B_lo(t+2)@ph4(t)=4];
//   drains 8 = all tile-(t+1) units before ph1(t+1) reads them. WAR: every
//   re-stage is >=1 barrier after its region's last reader's lgkm(0).
// ---------------------------------------------------------------------------
__global__ __launch_bounds__(512, 2) void gemm256(
    const bf16_t* __restrict__ A, const bf16_t* __restrict__ B,
    const float* __restrict__ bias, float* __restrict__ C,
    int M, int N, int K) {
  __shared__ __attribute__((aligned(16))) char lds[131072];

  const int tid = threadIdx.x;
  const int lane = tid & 63;
  const int wave = tid >> 6;
  const int wm = wave >> 2;   // 0..1  (row half of tile)
  const int wn = wave & 3;    // 0..3  (col quarter of tile)

  // XCD-aware bijective swizzle
  int nwg = gridDim.x;
  int wg = blockIdx.x;
  if ((nwg & 7) == 0) { int cpx = nwg >> 3; wg = (wg & 7) * cpx + (wg >> 3); }
  const int ntn = N / BN;
  const int tm = wg / ntn;
  const int tn = wg % ntn;

  const size_t Kb = (size_t)K * 2;
  const char* gApan = (const char*)A + (size_t)tm * BM * Kb;
  const char* gBpan = (const char*)B + (size_t)tn * BN * Kb;
  const size_t rowHi = (size_t)128 * Kb;   // row-half offset in global

  // ---- read bases: row&7 == lane&7 (all row bases are multiples of 8) ----
  const int l7 = lane & 7;
  const int hi = lane >> 4;
  const int c0b = ((hi ^ l7) << 4);          // ks=0 chunk byte
  const int c1b = (((hi + 4) ^ l7) << 4);    // ks=1 chunk byte
  const int aB0 = wm * 16384 + (lane & 15) * 128 + c0b;  // + r*8192 + i*2048
  const int aB1 = wm * 16384 + (lane & 15) * 128 + c1b;
  const int bB0 = 32768 + (wn >> 1) * 16384 + (wn & 1) * 8192 +
                  (lane & 15) * 128 + c0b;               // + c*4096 + j*2048
  const int bB1 = 32768 + (wn >> 1) * 16384 + (wn & 1) * 8192 +
                  (lane & 15) * 128 + c1b;

  // ---- staging: thread covers 2x16B of a 16KB unit; row_l = off>>7 ----
  // src chunk = (lane&7) ^ (row_l&7) = (lane&7) ^ ((lane>>3)&7)
  size_t srcoff[2];
  int ldst[2];
#pragma unroll
  for (int s = 0; s < 2; ++s) {
    int row_l = (wave * 2 + s) * 8 + (lane >> 3);
    int csrc = (lane & 7) ^ ((lane >> 3) & 7);
    srcoff[s] = (size_t)row_l * Kb + (size_t)(csrc << 4);
    ldst[s] = (wave * 2 + s) * 1024;
  }

#define STAGE_U(dstc, pan, rowoff, kbyte)                                     \
  {                                                                           \
    gload_lds16((pan) + (rowoff) + srcoff[0] + (size_t)(kbyte),               \
                lds + (dstc) + ldst[0]);                                      \
    gload_lds16((pan) + (rowoff) + srcoff[1] + (size_t)(kbyte),               \
                lds + (dstc) + ldst[1]);                                      \
  }
#define RD_A(r_)                                                              \
  _Pragma("unroll") for (int i_ = 0; i_ < 4; ++i_) {                          \
    af[i_][0] = *(const bf16x8*)(Lb + aB0 + (r_) * 8192 + i_ * 2048);         \
    af[i_][1] = *(const bf16x8*)(Lb + aB1 + (r_) * 8192 + i_ * 2048);         \
  }
#define RD_BC(dst, c_)                                                        \
  _Pragma("unroll") for (int j_ = 0; j_ < 2; ++j_) {                          \
    dst[j_][0] = *(const bf16x8*)(Lb + bB0 + (c_) * 4096 + j_ * 2048);        \
    dst[j_][1] = *(const bf16x8*)(Lb + bB1 + (c_) * 4096 + j_ * 2048);        \
  }
#define MFMAQ(r_, c_, bset)                                                   \
  __builtin_amdgcn_s_setprio(1);                                              \
  _Pragma("unroll") for (int i_ = 0; i_ < 4; ++i_)                            \
      _Pragma("unroll") for (int j_ = 0; j_ < 2; ++j_) {                      \
        acc[(r_) * 4 + i_][(c_) * 2 + j_] =                                   \
            __builtin_amdgcn_mfma_f32_16x16x32_bf16(                          \
                af[i_][0], bset[j_][0], acc[(r_) * 4 + i_][(c_) * 2 + j_],    \
                0, 0, 0);                                                     \
        acc[(r_) * 4 + i_][(c_) * 2 + j_] =                                   \
            __builtin_amdgcn_mfma_f32_16x16x32_bf16(                          \
                af[i_][1], bset[j_][1], acc[(r_) * 4 + i_][(c_) * 2 + j_],    \
                0, 0, 0);                                                     \
      }                                                                       \
  __builtin_amdgcn_s_setprio(0);
#define WAIT_LGKM(n) asm volatile("s_waitcnt lgkmcnt(" #n ")" ::: "memory")
#define WAIT_VM(n)   asm volatile("s_waitcnt vmcnt(" #n ")" ::: "memory")
#define BAR()        __builtin_amdgcn_s_barrier()

  f32x4 acc[8][4];
#pragma unroll
  for (int a = 0; a < 8; ++a)
#pragma unroll
    for (int j = 0; j < 4; ++j) acc[a][j] = (f32x4)0.0f;

  const int NT = K / BK;

  // ---- prologue: tile0 all 4 units + tile1 A_lo/B_lo; leave 4 in flight ----
  STAGE_U(0,     gApan, 0,     0);
  STAGE_U(16384, gApan, rowHi, 0);
  STAGE_U(32768, gBpan, 0,     0);
  STAGE_U(49152, gBpan, rowHi, 0);
  if (NT > 1) {
    STAGE_U(65536,         gApan, 0, 128);
    STAGE_U(65536 + 32768, gBpan, 0, 128);
    WAIT_VM(4);
  } else {
    WAIT_VM(0);
  }
  BAR();

  bf16x8 af[4][2], b0[2][2], b1[2][2];

  for (int t = 0; t < NT; ++t) {
    const int bb = (t & 1) << 16;
    const int nb = bb ^ 65536;
    const char* Lb = lds + bb;
    const size_t kb1 = (size_t)(t + 1) * 128;
    const size_t kb2 = (size_t)(t + 2) * 128;
    const bool st1 = (t + 1) < NT;
    const bool st2 = (t + 2) < NT;

    // ---- ph1: quadrant (r0,c0); 12 reads; stage A_hi(t+1) ----
    RD_A(0);
    RD_BC(b0, 0);
    if (st1) STAGE_U(nb + 16384, gApan, rowHi, kb1);
    WAIT_LGKM(8);
    BAR();
    WAIT_LGKM(0);
    MFMAQ(0, 0, b0);
    BAR();

    // ---- ph2: quadrant (r0,c1); 4 reads; stage B_hi(t+1) ----
    RD_BC(b1, 1);
    if (st1) STAGE_U(nb + 49152, gBpan, rowHi, kb1);
    BAR();
    WAIT_LGKM(0);
    MFMAQ(0, 1, b1);
    BAR();

    // ---- ph3: quadrant (r1,c1); 8 reads; no stage ----
    RD_A(1);
    BAR();
    WAIT_LGKM(0);
    MFMAQ(1, 1, b1);
    BAR();

    // ---- ph4: quadrant (r1,c0); 0 reads (b0 live); stage A_lo/B_lo(t+2) ----
    if (st2) {
      STAGE_U(bb,         gApan, 0, kb2);
      STAGE_U(bb + 32768, gBpan, 0, kb2);
    }
    MFMAQ(1, 0, b0);
    if (st2) { WAIT_VM(4); } else { WAIT_VM(0); }
    BAR();
  }
#undef STAGE_U
#undef RD_A
#undef RD_BC
#undef MFMAQ
#undef WAIT_LGKM
#undef WAIT_VM
#undef BAR

  // ---- epilogue: bias + store. C/D: col=lane&15, row=(lane>>4)*4+r ----
  const int row0 = tm * BM + wm * 128;
  const int col0 = tn * BN + wn * 64;
#pragma unroll
  for (int j = 0; j < 4; ++j) {
    int c = col0 + j * 16 + (lane & 15);
    float bv = bias[c];
#pragma unroll
    for (int a = 0; a < 8; ++a) {
      int ch = a >> 2, i = a & 3;
      int rbase = row0 + ch * 64 + i * 16 + ((lane >> 4) << 2);
#pragma unroll
      for (int r = 0; r < 4; ++r)
        C[(size_t)(rbase + r) * N + c] = acc[a][j][r] + bv;
    }
  }
}

// ---------------------------------------------------------------------------
// fallback: naive fp32 (only if workspace/shape unsuitable — correctness net)
// ---------------------------------------------------------------------------
__global__ void fallback_gemm(const float* __restrict__ x,
                              const float* __restrict__ w,
                              const float* __restrict__ s,
                              const float* __restrict__ b,
                              float* __restrict__ out, int M, int N, int K) {
  int o = blockIdx.x * blockDim.x + threadIdx.x;
  if (o >= M * N) return;
  int m = o / N, n = o % N;
  const float* xr = x + (size_t)m * K;
  const float* wr = w + (size_t)n * K;
  float acc = 0.f;
  for (int k = 0; k < K; ++k) acc += xr[k] * wr[k];
  out[o] = acc * s[n] + b[n];
}

extern "C" void kernel_launch(void* const* d_in, const int* in_sizes, int n_in,
                              void* d_out, int out_size, void* d_ws,
                              size_t ws_size, hipStream_t stream) {
  const float* x = (const float*)d_in[0];
  const float* w = (const float*)d_in[1];
  const float* sc = (const float*)d_in[2];
  const float* bias = (const float*)d_in[3];
  float* out = (float*)d_out;

  const int N = in_sizes[2];        // out_features (weight_scale length)
  const int K = in_sizes[1] / N;    // in_features
  const int M = in_sizes[0] / K;    // tokens

  const size_t need = ((size_t)M * K + (size_t)N * K) * sizeof(bf16_t);
  const bool fast = (ws_size >= need) && (M % BM == 0) && (N % BN == 0) &&
                    (K % BK == 0) && (K / BK >= 1);

  if (fast) {
    bf16_t* xb = (bf16_t*)d_ws;
    bf16_t* wb = xb + (size_t)M * K;

    int n8x = (M * K) / 8;
    int n8w = (N * K) / 8;
    const int gx = 2048;
    cvt_kernel<<<gx + 2048, 256, 0, stream>>>(x, xb, n8x, w, sc, wb, K / 8,
                                              n8w, gx);

    dim3 grid((M / BM) * (N / BN));
    gemm256<<<grid, 512, 0, stream>>>(xb, wb, bias, out, M, N, K);
  } else {
    int total = M * N;
    fallback_gemm<<<(total + 255) / 256, 256, 0, stream>>>(x, w, sc, bias, out,
                                                           M, N, K);
  }
}